// Round 14
// baseline (272.623 us; speedup 1.0000x reference)
//
#include <hip/hip_runtime.h>
#include <hip/hip_bf16.h>

// AttnBlock2D decoupled-GEMM pipeline, R14. B=4, C=512, N=4096 per batch.
// Numerics = R13 (verified: absmax 2.9e-3):
//   kth/qth fp16 -> per-row int8 (kt8/qt8 + sk/sq), vc fp16,
//   P = exp2(acc*sk_i*sq_j - 4) fp16 unnorm, otab fp16 halves, out = Wo_dup.otab*linv+bo.
// R14 core: 256x256, 8 waves (wave 128x64), BK=64, DOUBLE-BUFFERED 2x64KB LDS,
// issue-early staging: { stage(t+1,buf^1); compute(t,buf); __syncthreads(); }
// -> L2 latency hides under 64 MFMA/wave; single barrier per K-step.

typedef __attribute__((ext_vector_type(4))) float f32x4;
typedef __attribute__((ext_vector_type(4))) int i32x4;
typedef _Float16 half8 __attribute__((ext_vector_type(8)));
typedef __attribute__((ext_vector_type(4))) short short4v;
typedef __attribute__((ext_vector_type(8))) signed char schar8;

#define SQRT_QS 0.2525200f   // sqrt(log2(e)/sqrt(512))

__device__ __forceinline__ unsigned short f2h(float f) {
  _Float16 h = (_Float16)f;
  return __builtin_bit_cast(unsigned short, h);
}

__device__ __forceinline__ void gll16(const void* g, void* l) {
  __builtin_amdgcn_global_load_lds((const __attribute__((address_space(1))) void*)g,
                                   (__attribute__((address_space(3))) void*)l, 16, 0, 0);
}

#define MFMA_F16(d, va, vb) \
  d = __builtin_amdgcn_mfma_f32_16x16x32_f16(va, vb, d, 0, 0, 0)
#define MFMA_I8(d, va, vb) \
  d = __builtin_amdgcn_mfma_i32_16x16x64_i8(va, vb, d, 0, 0, 0)

// ============ 256x256 dbuf fp16 core (8 waves, BK=64, 2x64KB LDS) ============
// Buffer: A 256x128B (32KB) | B 256x128B (32KB). Rows 128B, (row&7)<<4 swizzle.
// Wave (wm=w>>2, wn=w&3) owns rows wm*128..+127, cols wn*64..+63.
__device__ __forceinline__ void gemm_db(
    const short* __restrict__ A, int lda,
    const short* __restrict__ B, int ldb,
    int nkt, char* sm, f32x4 (&acc)[8][4]) {
  const int tid = threadIdx.x, w = tid >> 6, lane = tid & 63;
  const int g = lane >> 4, l15 = lane & 15;
  const int wm = w >> 2, wn = w & 3;
  const int swz = (l15 & 7) << 4;
  const int brow = (wn & 1) << 6;

  auto stage = [&](int t, int buf) {
    if (t >= nkt) return;
    char* base = sm + (buf << 16);
#pragma unroll
    for (int c = 0; c < 4; ++c) {            // A: 32 chunks of 1KB
      int chunk = c * 8 + w;
      int o = (chunk << 10) | (lane << 4);
      int row = o >> 7, cb = (o & 127) ^ ((row & 7) << 4);
      gll16((const char*)A + (size_t)row * (lda * 2) + (size_t)t * 128 + cb,
            base + (chunk << 10));
    }
#pragma unroll
    for (int c = 0; c < 4; ++c) {            // B
      int chunk = c * 8 + w;
      int o = (chunk << 10) | (lane << 4);
      int row = o >> 7, cb = (o & 127) ^ ((row & 7) << 4);
      gll16((const char*)B + (size_t)row * (ldb * 2) + (size_t)t * 128 + cb,
            base + 32768 + (chunk << 10));
    }
  };

  stage(0, 0);
  __syncthreads();
  for (int t = 0; t < nkt; ++t) {
    const int buf = t & 1;
    stage(t + 1, buf ^ 1);                   // issue early; hides under MFMA
    const char* SA = sm + (buf << 16) + (wm << 14);
    const char* SB = sm + (buf << 16) + 32768 + ((wn >> 1) << 14);
#pragma unroll
    for (int ks = 0; ks < 2; ++ks) {
      half8 a[8], bb[4];
#pragma unroll
      for (int i = 0; i < 8; ++i)
        a[i] = *(const half8*)(SA + (i * 16 + l15) * 128 + ((ks * 64 + g * 16) ^ swz));
#pragma unroll
      for (int nf = 0; nf < 4; ++nf)
        bb[nf] = *(const half8*)(SB + (brow + nf * 16 + l15) * 128 +
                                 ((ks * 64 + g * 16) ^ swz));
      __builtin_amdgcn_s_setprio(1);
#pragma unroll
      for (int i = 0; i < 8; ++i)
#pragma unroll
        for (int nf = 0; nf < 4; ++nf)
          MFMA_F16(acc[i][nf], a[i], bb[nf]);
      __builtin_amdgcn_s_setprio(0);
    }
    __syncthreads();                         // drains stage(t+1); next tile ready
  }
}

// ============ 256x256 dbuf INT8 core (BK=128, byte-identical layout) ============
__device__ __forceinline__ void gemm_db_i8(
    const signed char* __restrict__ A, int ldaB,
    const signed char* __restrict__ B, int ldbB,
    int nkt, char* sm, i32x4 (&acc)[8][4]) {
  const int tid = threadIdx.x, w = tid >> 6, lane = tid & 63;
  const int g = lane >> 4, l15 = lane & 15;
  const int wm = w >> 2, wn = w & 3;
  const int swz = (l15 & 7) << 4;
  const int brow = (wn & 1) << 6;

  auto stage = [&](int t, int buf) {
    if (t >= nkt) return;
    char* base = sm + (buf << 16);
#pragma unroll
    for (int c = 0; c < 4; ++c) {
      int chunk = c * 8 + w;
      int o = (chunk << 10) | (lane << 4);
      int row = o >> 7, cb = (o & 127) ^ ((row & 7) << 4);
      gll16((const char*)A + (size_t)row * ldaB + (size_t)t * 128 + cb,
            base + (chunk << 10));
    }
#pragma unroll
    for (int c = 0; c < 4; ++c) {
      int chunk = c * 8 + w;
      int o = (chunk << 10) | (lane << 4);
      int row = o >> 7, cb = (o & 127) ^ ((row & 7) << 4);
      gll16((const char*)B + (size_t)row * ldbB + (size_t)t * 128 + cb,
            base + 32768 + (chunk << 10));
    }
  };

  stage(0, 0);
  __syncthreads();
  for (int t = 0; t < nkt; ++t) {
    const int buf = t & 1;
    stage(t + 1, buf ^ 1);
    const char* SA = sm + (buf << 16) + (wm << 14);
    const char* SB = sm + (buf << 16) + 32768 + ((wn >> 1) << 14);
#pragma unroll
    for (int ks = 0; ks < 2; ++ks) {
      i32x4 a[8], bb[4];
#pragma unroll
      for (int i = 0; i < 8; ++i)
        a[i] = *(const i32x4*)(SA + (i * 16 + l15) * 128 + ((ks * 64 + g * 16) ^ swz));
#pragma unroll
      for (int nf = 0; nf < 4; ++nf)
        bb[nf] = *(const i32x4*)(SB + (brow + nf * 16 + l15) * 128 +
                                 ((ks * 64 + g * 16) ^ swz));
      __builtin_amdgcn_s_setprio(1);
#pragma unroll
      for (int i = 0; i < 8; ++i)
#pragma unroll
        for (int nf = 0; nf < 4; ++nf)
          MFMA_I8(acc[i][nf], a[i], bb[nf]);
      __builtin_amdgcn_s_setprio(0);
    }
    __syncthreads();
  }
}

// ---------------------------------------------------------------- cvt weights
__global__ __launch_bounds__(256) void cvt_w_kernel(
    const float* __restrict__ wk, const float* __restrict__ wq,
    const float* __restrict__ wv, const float* __restrict__ wo,
    short* __restrict__ o) {
  int z = blockIdx.y;
  const float* s = (z == 0) ? wk : (z == 1) ? wq : (z == 2) ? wv : wo;
  int i = blockIdx.x * 256 + threadIdx.x;
  float4 f = ((const float4*)s)[i];
  short4v v;
  v[0] = (short)f2h(f.x); v[1] = (short)f2h(f.y);
  v[2] = (short)f2h(f.z); v[3] = (short)f2h(f.w);
  if (z < 3) {
    *(short4v*)(o + z * 262144 + i * 4) = v;
  } else {                       // Wo duplicated along K: wdup[co][1024]
    int idx = i * 4, co = idx >> 9, cc = idx & 511;
    short* base = o + 786432 + co * 1024 + cc;
    *(short4v*)base = v;
    *(short4v*)(base + 512) = v;
  }
}

// --------------------------------------------------- transpose inp -> x_t fp16
__global__ __launch_bounds__(256) void transpose_x_kernel(
    const float* __restrict__ inp, short* __restrict__ xt) {
  __shared__ float t[32][33];
  int tx = threadIdx.x, ty = threadIdx.y;
  int n0 = blockIdx.x * 32, c0 = blockIdx.y * 32, b = blockIdx.z;
  const float* src = inp + ((size_t)(b * 512 + c0)) * 4096 + n0;
#pragma unroll
  for (int r = 0; r < 4; ++r) t[ty + r * 8][tx] = src[(ty + r * 8) * 4096 + tx];
  __syncthreads();
  short* dst = xt + ((size_t)((b << 12) + n0)) * 512 + c0;
#pragma unroll
  for (int r = 0; r < 4; ++r) dst[(ty + r * 8) * 512 + tx] = (short)f2h(t[tx][ty + r * 8]);
}

// ------------------------------------------------- QKV projection (dbuf core)
// 384 blocks 1D. xt 256-row panel gg (0..63), xcd = gg&7; 6 consumers per panel:
// t 0,1: kth c-half t; t 2,3: qth c-half t-2; t 4,5: vc c-tile t-4.
__global__ __launch_bounds__(512, 2) void kqv_kernel(
    const short* __restrict__ xt,
    const short* __restrict__ wk, const short* __restrict__ wq, const short* __restrict__ wv,
    const float* __restrict__ bk, const float* __restrict__ bq, const float* __restrict__ bv,
    short* __restrict__ kth, short* __restrict__ qth,
    short* __restrict__ vc) {
  extern __shared__ char sm[];
  const int bid = blockIdx.x;
  const int xcd = bid & 7, s = bid >> 3;        // s: 0..47
  const int gg = (s / 6) * 8 + xcd;             // 0..63
  const int t = s % 6;
  const int z = t >> 1;                         // 0:k 1:q 2:v
  const short *A, *B;
  int arow0, brow0;
  if (z < 2) {
    arow0 = gg * 256;                           // n rows (256)
    brow0 = (t & 1) * 256;                      // c cols (256)
    A = xt + (size_t)arow0 * 512;
    B = ((z == 0) ? wk : wq) + (size_t)brow0 * 512;
  } else {
    arow0 = (t - 4) * 256;                      // c rows (256)
    brow0 = gg * 256;                           // n cols (256)
    A = wv + (size_t)arow0 * 512;
    B = xt + (size_t)brow0 * 512;
  }
  f32x4 acc[8][4] = {};
  gemm_db(A, 512, B, 512, 8, sm, acc);
  const int tid = threadIdx.x, w = tid >> 6, lane = tid & 63;
  const int gq = lane >> 4, l15 = lane & 15;
  const int wm = w >> 2, wn = w & 3;
#pragma unroll
  for (int mf = 0; mf < 8; ++mf)
#pragma unroll
    for (int nf = 0; nf < 4; ++nf)
#pragma unroll
      for (int r = 0; r < 4; ++r) {
        int row = wm * 128 + mf * 16 + gq * 4 + r;
        int col = wn * 64 + nf * 16 + l15;
        float v = acc[mf][nf][r];
        if (z == 2) {
          vc[(size_t)(arow0 + row) * 16384 + brow0 + col] =
              (short)f2h(v + bv[arow0 + row]);
        } else {
          short* dst = (z == 0) ? kth : qth;
          float bias = (z == 0) ? bk[brow0 + col] : bq[brow0 + col];
          dst[(size_t)(arow0 + row) * 512 + brow0 + col] = (short)f2h(v + bias);
        }
      }
}

// ---------------------- per-row int8 quantization (k and q, 32768 rows) ----------------------
__global__ __launch_bounds__(256) void quant_kernel(
    const short* __restrict__ src, signed char* __restrict__ dst,
    float* __restrict__ scl) {
  const int row = blockIdx.x * 4 + (threadIdx.x >> 6);
  const int lane = threadIdx.x & 63;
  half8 v = *(const half8*)(src + (size_t)row * 512 + lane * 8);
  float f[8];
  float m = 0.f;
#pragma unroll
  for (int e = 0; e < 8; ++e) { f[e] = (float)v[e]; m = fmaxf(m, fabsf(f[e])); }
#pragma unroll
  for (int off = 1; off < 64; off <<= 1) m = fmaxf(m, __shfl_xor(m, off));
  m = fmaxf(m, 1e-6f);
  const float inv = 127.0f / m;
  schar8 q;
#pragma unroll
  for (int e = 0; e < 8; ++e) q[e] = (signed char)(int)rintf(f[e] * inv);
  *(schar8*)(dst + (size_t)row * 512 + lane * 8) = q;
  if (lane == 0) scl[row] = m * (SQRT_QS / 127.0f);
}

// ------------------------- S-GEMM (i8 dbuf core) + exp2 + row partials -------------------------
// 1024 blocks 1D. xcd = (b,h); s = it(0..15) x jt(0..7); 256x256 tiles, K=512 i8 (4 steps).
__global__ __launch_bounds__(512, 2) void gemm_s_kernel(
    const signed char* __restrict__ kt8, const signed char* __restrict__ qt8,
    const float* __restrict__ sk, const float* __restrict__ sq,
    short* __restrict__ P, float* __restrict__ Lpart) {
  extern __shared__ char sm[];
  const int bid = blockIdx.x;
  const int xcd = bid & 7, s = bid >> 3;        // s: 0..127
  const int b = xcd >> 1, h = xcd & 1;
  const int it = s >> 3, jt = s & 7;
  const int i0 = it * 256, jt0 = jt * 256;
  const signed char* A = kt8 + ((size_t)((b << 12) + i0)) * 512;
  const signed char* B = qt8 + ((size_t)((b << 12) + h * 2048 + jt0)) * 512;
  i32x4 acc[8][4] = {};
  gemm_db_i8(A, 512, B, 512, 4, sm, acc);
  const int tid = threadIdx.x, w = tid >> 6, lane = tid & 63;
  const int gq = lane >> 4, l15 = lane & 15;
  const int wm = w >> 2, wn = w & 3;
  const float* skp = sk + (b << 12) + i0 + wm * 128;
  const float* sqp = sq + (b << 12) + h * 2048 + jt0;
  float sqc[4];
#pragma unroll
  for (int nf = 0; nf < 4; ++nf) sqc[nf] = sqp[wn * 64 + nf * 16 + l15];
  short* Pb = P + (size_t)h * 33554432 + ((size_t)((b << 12) + i0)) * 2048 + jt0;
  float psum[8][4];
#pragma unroll
  for (int mf = 0; mf < 8; ++mf)
#pragma unroll
    for (int r = 0; r < 4; ++r) psum[mf][r] = 0.f;
#pragma unroll
  for (int mf = 0; mf < 8; ++mf) {
    float skr[4];
#pragma unroll
    for (int r = 0; r < 4; ++r) skr[r] = skp[mf * 16 + gq * 4 + r];
#pragma unroll
    for (int nf = 0; nf < 4; ++nf)
#pragma unroll
      for (int r = 0; r < 4; ++r) {
        float p = exp2f((float)acc[mf][nf][r] * skr[r] * sqc[nf] - 4.0f);
        psum[mf][r] += p;
        int row = wm * 128 + mf * 16 + gq * 4 + r;
        int col = wn * 64 + nf * 16 + l15;
        Pb[(size_t)row * 2048 + col] = (short)f2h(p);
      }
  }
  const int jp = (h * 2048 + jt0 + wn * 64) >> 6;
  float* Lp = Lpart + (((size_t)b * 64 + jp) << 12) + i0 + wm * 128;
#pragma unroll
  for (int mf = 0; mf < 8; ++mf)
#pragma unroll
    for (int r = 0; r < 4; ++r) {
      float ss = psum[mf][r];
      ss += __shfl_xor(ss, 1); ss += __shfl_xor(ss, 2);
      ss += __shfl_xor(ss, 4); ss += __shfl_xor(ss, 8);
      if (l15 == 0) Lp[mf * 16 + gq * 4 + r] = ss;
    }
}

// ------------------------------- PV-GEMM (fp16 dbuf core, K=2048) -------------------------------
// 256 blocks 1D. xcd = (b,h); s = it(0..15) x ct(0..1); 256x256 tiles, 32 K-steps.
__global__ __launch_bounds__(512, 2) void gemm_pv_kernel(
    const short* __restrict__ P, const short* __restrict__ vc,
    short* __restrict__ otab) {
  extern __shared__ char sm[];
  const int bid = blockIdx.x;
  const int xcd = bid & 7, s = bid >> 3;        // s: 0..31
  const int b = xcd >> 1, h = xcd & 1;
  const int it = s >> 1, ct = s & 1;
  const int i0 = it * 256, c0 = ct * 256;
  const short* A = P + (size_t)h * 33554432 + ((size_t)((b << 12) + i0)) * 2048;
  const short* B = vc + (size_t)c0 * 16384 + (b << 12) + h * 2048;
  f32x4 acc[8][4] = {};
  gemm_db(A, 2048, B, 16384, 32, sm, acc);
  const int tid = threadIdx.x, w = tid >> 6, lane = tid & 63;
  const int gq = lane >> 4, l15 = lane & 15;
  const int wm = w >> 2, wn = w & 3;
  short* Ob = otab + ((size_t)((b << 12) + i0)) * 1024 + h * 512 + c0;
#pragma unroll
  for (int mf = 0; mf < 8; ++mf)
#pragma unroll
    for (int nf = 0; nf < 4; ++nf)
#pragma unroll
      for (int r = 0; r < 4; ++r) {
        int row = wm * 128 + mf * 16 + gq * 4 + r;
        int col = wn * 64 + nf * 16 + l15;
        Ob[(size_t)row * 1024 + col] = (short)f2h(acc[mf][nf][r]);
      }
}

// ------------------------------------------------------------------ l reduce
__global__ __launch_bounds__(256) void lred_kernel(
    const float* __restrict__ Lpart, float* __restrict__ linv) {
  int i = blockIdx.x * 256 + threadIdx.x;      // 16384 = (b,i)
  int b = i >> 12;
  float s = 0.f;
#pragma unroll 8
  for (int jp = 0; jp < 64; ++jp) s += Lpart[(((size_t)b * 64 + jp) << 12) + (i & 4095)];
  linv[i] = 1.0f / s;
}

// ------------------------------ final projection (fp16 dbuf core, K=1024) ------------------------------
// 128 blocks 1D. xcd = (b, co-half); s = nt(0..15).
__global__ __launch_bounds__(512, 2) void gemm_out_kernel(
    const short* __restrict__ wdup, const short* __restrict__ otab,
    const float* __restrict__ bo, const float* __restrict__ linv,
    float* __restrict__ out) {
  extern __shared__ char sm[];
  const int bid = blockIdx.x;
  const int xcd = bid & 7, nt = bid >> 3;       // nt: 0..15
  const int b = xcd >> 1, coh = xcd & 1;
  const int arow0 = coh * 256;                  // co
  const int bn0 = nt * 256;                     // n within batch
  const short* A = wdup + (size_t)arow0 * 1024;
  const short* B = otab + ((size_t)((b << 12) + bn0)) * 1024;
  f32x4 acc[8][4] = {};
  gemm_db(A, 1024, B, 1024, 16, sm, acc);
  const int tid = threadIdx.x, w = tid >> 6, lane = tid & 63;
  const int gq = lane >> 4, l15 = lane & 15;
  const int wm = w >> 2, wn = w & 3;
#pragma unroll
  for (int mf = 0; mf < 8; ++mf) {
    int co = arow0 + wm * 128 + mf * 16 + gq * 4;
#pragma unroll
    for (int nf = 0; nf < 4; ++nf) {
      int nl = bn0 + wn * 64 + nf * 16 + l15;
      float li = linv[(b << 12) + nl];
#pragma unroll
      for (int r = 0; r < 4; ++r)
        out[((size_t)(b * 512 + co + r) << 12) + nl] = acc[mf][nf][r] * li + bo[co + r];
    }
  }
}

// ---------------------------------------------------------------------- host
extern "C" void kernel_launch(void* const* d_in, const int* in_sizes, int n_in,
                              void* d_out, int out_size, void* d_ws, size_t ws_size,
                              hipStream_t stream) {
  const float* inp = (const float*)d_in[0];
  const float* Wk = (const float*)d_in[1];
  const float* bk = (const float*)d_in[2];
  const float* Wq = (const float*)d_in[3];
  const float* bq = (const float*)d_in[4];
  const float* Wv = (const float*)d_in[5];
  const float* bv = (const float*)d_in[6];
  const float* Wo = (const float*)d_in[7];
  const float* bo = (const float*)d_in[8];
  float* out = (float*)d_out;
  char* ws = (char*)d_ws;
  const size_t MB = 1048576;
  // layout (227 MB): kt8 0..8 | qt8 8..16 | sk/sq 16..16.125 | vc 32..48 |
  //   wb 48..51 | xt 51..67 (Lpart/linv alias) |
  //   P 67..195 (kth 67..83, qth 83..99 live only kqv->quant) | otab 195..227
  signed char* kt8 = (signed char*)(ws);
  signed char* qt8 = (signed char*)(ws + 8 * MB);
  float* sk    = (float*)(ws + 16 * MB);          // sq = sk + 16384
  short* vc    = (short*)(ws + 32 * MB);
  short* wb    = (short*)(ws + 48 * MB);
  short* xt    = (short*)(ws + 51 * MB);
  float* Lpart = (float*)(ws + 51 * MB);
  float* linv  = (float*)(ws + 55 * MB);
  short* P     = (short*)(ws + 67 * MB);
  short* kth   = (short*)(ws + 67 * MB);          // aliases P (consumed pre-S)
  short* qth   = (short*)(ws + 83 * MB);
  short* otab  = (short*)(ws + 195 * MB);

  (void)in_sizes; (void)n_in; (void)out_size; (void)ws_size;

  hipFuncSetAttribute((const void*)kqv_kernel,
                      hipFuncAttributeMaxDynamicSharedMemorySize, 131072);
  hipFuncSetAttribute((const void*)gemm_s_kernel,
                      hipFuncAttributeMaxDynamicSharedMemorySize, 131072);
  hipFuncSetAttribute((const void*)gemm_pv_kernel,
                      hipFuncAttributeMaxDynamicSharedMemorySize, 131072);
  hipFuncSetAttribute((const void*)gemm_out_kernel,
                      hipFuncAttributeMaxDynamicSharedMemorySize, 131072);

  cvt_w_kernel<<<dim3(256, 4), 256, 0, stream>>>(Wk, Wq, Wv, Wo, wb);
  transpose_x_kernel<<<dim3(128, 16, 4), dim3(32, 8, 1), 0, stream>>>(inp, xt);
  kqv_kernel<<<384, 512, 131072, stream>>>(
      xt, wb, wb + 262144, wb + 524288, bk, bq, bv, kth, qth, vc);
  quant_kernel<<<8192, 256, 0, stream>>>(kth, kt8, sk);   // kth/qth contiguous
  gemm_s_kernel<<<1024, 512, 131072, stream>>>(
      kt8, qt8, sk, sk + 16384, P, Lpart);
  gemm_pv_kernel<<<256, 512, 131072, stream>>>(P, vc, otab);
  lred_kernel<<<64, 256, 0, stream>>>(Lpart, linv);
  gemm_out_kernel<<<128, 512, 131072, stream>>>(wb + 786432, otab, bo, linv, out);
}